// Round 12
// baseline (1150.543 us; speedup 1.0000x reference)
//
#include <hip/hip_runtime.h>
#include <hip/hip_bf16.h>

typedef _Float16 f16;
typedef __attribute__((ext_vector_type(2)))  _Float16 h2;
typedef __attribute__((ext_vector_type(8)))  _Float16 f16x8;
typedef __attribute__((ext_vector_type(4)))  _Float16 f16x4;
typedef __attribute__((ext_vector_type(16))) float    f32x16;

#define HW16K 16384

__device__ __forceinline__ void gld16(const void* g, void* l) {
    __builtin_amdgcn_global_load_lds((const __attribute__((address_space(1))) void*)g,
                                     (__attribute__((address_space(3))) void*)l, 16, 0, 0);
}

// ---------------------------------------------------------------------------
// Implicit-GEMM 3x3 conv via v_mfma_f32_32x32x16_f16.  (r11 champion, frozen)
// ---------------------------------------------------------------------------
template <int DIL, int PXW, int MFW, int MODE>
__global__ __launch_bounds__(512, 4) void conv_mfma(
    const f16* __restrict__ in, int inYe, int inXe, int inCs, int inPad,
    const f16* __restrict__ wp, const float* __restrict__ bias,
    f16* __restrict__ out, int outYe, int outXe, int outCs, int outPad, int outCoOff,
    float* __restrict__ dout,
    int Ci16, int CoPad)
{
    constexpr int Wext = 128 + 2 * DIL;
    constexpr int NR   = (DIL == 1) ? 4 : 6;
    constexpr int CH   = NR * Wext * 2;        // 16B chunks per K-tile
    constexpr int CHB  = CH * 16;
    constexpr int TI   = (CH + 511) / 512;
    __shared__ __align__(16) char smem[2 * CHB];

    const int tid  = threadIdx.x;
    const int lane = tid & 63;
    const int wv   = tid >> 6;
    const int col  = lane & 31;
    const int hi   = lane >> 5;
    const int t    = wv >> 2;                  // output row within block
    const int wq   = wv & 3;
    constexpr int CPW = PXW;                   // co-slots per row-group
    const int pp   = wq / CPW;                 // px-group index
    const int c    = wq % CPW;                 // co-slot index
    const int cb0  = blockIdx.y * (32 * PXW * MFW);

    const int g  = blockIdx.x;                 // XCD-swizzled (b, ychunk)
    const int n  = (g & 7) * 64 + (g >> 3);
    const int b  = n >> 6;
    const int y0 = (n & 63) * 2;

    const f16* inb = in + (size_t)b * inYe * inXe * inCs;

    auto stage = [&](int kt, int bufi) {
        const int ci0 = kt * 16;
        char* sb = smem + bufi * CHB;
#pragma unroll
        for (int i = 0; i < TI; ++i) {
            int cc = i * 512 + tid;
            if (cc < CH) {
                int r   = cc / (Wext * 2);
                int rem = cc - r * (Wext * 2);
                int px = rem >> 1, half = rem & 1;
                int yin = (DIL == 1) ? (y0 - 1 + r)
                                     : (y0 + (r & 1) + ((r >> 1) - 1) * DIL);
                const f16* src = inb
                    + ((size_t)(yin + inPad) * inXe + (inPad - DIL + px)) * inCs
                    + ci0 + half * 8;
                gld16(src, sb + cc * 16);
            }
        }
    };

    f32x16 acc[PXW][MFW] = {};

    stage(0, 0);
    __syncthreads();
    for (int kt = 0; kt < Ci16; ++kt) {
        if (kt + 1 < Ci16) stage(kt + 1, (kt + 1) & 1);
        const char* sb = smem + (kt & 1) * CHB;
        const f16* wkt = wp + (size_t)kt * 9 * CoPad * 16 + hi * 8;

        if constexpr (MFW == 1) {
            f16x8 wfr[9];
#pragma unroll
            for (int k9 = 0; k9 < 9; ++k9)
                wfr[k9] = *(const f16x8*)(wkt + (size_t)k9 * CoPad * 16 +
                                          (cb0 + 32 * c + col) * 16);
#pragma unroll
            for (int ky = 0; ky < 3; ++ky) {
#pragma unroll
                for (int kx = 0; kx < 3; ++kx) {
                    const int rrow = (DIL == 1) ? (t + ky) : (ky * 2 + t);
#pragma unroll
                    for (int p = 0; p < PXW; ++p) {
                        const f16x8 bfrag = *(const f16x8*)(sb +
                            ((rrow * Wext + 32 * (PXW * pp + p) + col + kx * DIL) * 32 + hi * 16));
                        acc[p][0] = __builtin_amdgcn_mfma_f32_32x32x16_f16(
                            wfr[ky * 3 + kx], bfrag, acc[p][0], 0, 0, 0);
                    }
                }
            }
        } else {
#pragma unroll
            for (int ky = 0; ky < 3; ++ky) {
#pragma unroll
                for (int kx = 0; kx < 3; ++kx) {
                    const int rrow = (DIL == 1) ? (t + ky) : (ky * 2 + t);
                    f16x8 bfr[PXW];
#pragma unroll
                    for (int p = 0; p < PXW; ++p)
                        bfr[p] = *(const f16x8*)(sb +
                            ((rrow * Wext + 32 * (PXW * pp + p) + col + kx * DIL) * 32 + hi * 16));
                    const f16* wtap = wkt + (size_t)(ky * 3 + kx) * CoPad * 16;
#pragma unroll
                    for (int m = 0; m < MFW; ++m) {
                        const f16x8 afrag =
                            *(const f16x8*)(wtap + (cb0 + 32 * (c * MFW + m) + col) * 16);
#pragma unroll
                        for (int p = 0; p < PXW; ++p)
                            acc[p][m] = __builtin_amdgcn_mfma_f32_32x32x16_f16(
                                afrag, bfr[p], acc[p][m], 0, 0, 0);
                    }
                }
            }
        }
        __syncthreads();
    }

    // ---- epilogue ----
    const int y = y0 + t;
    if constexpr (MODE == 0) {
#pragma unroll
        for (int p = 0; p < PXW; ++p) {
            const int x = 32 * (PXW * pp + p) + col;
            const size_t pixbase =
                (((size_t)b * outYe + (y + outPad)) * outXe + (outPad + x)) * outCs + outCoOff;
#pragma unroll
            for (int m = 0; m < MFW; ++m) {
#pragma unroll
                for (int eq = 0; eq < 4; ++eq) {
                    const int co = cb0 + 32 * (c * MFW + m) + 8 * eq + 4 * hi;
                    f16x4 h;
#pragma unroll
                    for (int s = 0; s < 4; ++s) {
                        float v = acc[p][m][4 * eq + s] + bias[co + s];
                        v = (v >= 0.f) ? v : 0.1f * v;
                        h[s] = (f16)v;
                    }
                    *(f16x4*)(out + pixbase + co) = h;
                }
            }
        }
    } else {
        if (hi == 0) {
            const int x = 32 * pp + col;
#pragma unroll
            for (int s = 0; s < 2; ++s) {
                float v = acc[0][0][s] + bias[s];
                const size_t oi = (((size_t)b * 2 + s) * 128 + y) * 128 + x;
                if constexpr (MODE == 1) {
                    dout[oi] = v;
                    const size_t pixbase =
                        (((size_t)b * outYe + (y + outPad)) * outXe + (outPad + x)) * outCs + outCoOff;
                    out[pixbase + s] = (f16)v;
                } else {
                    v = (v >= 0.f) ? v : 0.1f * v;
                    dout[oi] += v;
                }
            }
        }
    }
}

// ---------------------------------------------------------------------------
// Correlation v4: NHWC channel-major f16 layouts, 16B f16x8 loads, dot2 math.
// PX1n: [b][128][128][128ch] f16   PX2n: [b][136][136][128ch] f16 (4-px border)
// Pixel base = 256B-aligned; chunk offset = c4*16B -> all loads 16B-aligned.
// Grid (512 XCD-swizzled, 3 dy-groups). Per c4-iter: 1+27 16B loads, 108 dot2.
// Writes f16 into IN0 channels 128..208.
// ---------------------------------------------------------------------------
__global__ __launch_bounds__(256) void corr_k(const f16* __restrict__ px1,
                                              const f16* __restrict__ px2,
                                              f16* __restrict__ in0) {
    const int g = blockIdx.x;                  // bijective XCD swizzle
    const int n = (g & 7) * 64 + (g >> 3);
    const int b = n >> 6;
    const int x = threadIdx.x & 127;
    const int y = (n & 63) * 2 + (threadIdx.x >> 7);
    const int dy0 = blockIdx.y * 3;

    const f16* p1 = px1 + ((size_t)(b * 128 + y) * 128 + x) * 128;
    const f16* p2 = px2 + ((size_t)(b * 136 + (y + dy0)) * 136 + x) * 128;
    f16* orow = in0 + (((size_t)b * 130 + (y + 1)) * 130 + (x + 1)) * 224 + 128;

    float acc[3][9] = {};
    for (int c4 = 0; c4 < 16; ++c4) {
        const f16x8 a1 = *(const f16x8*)(p1 + c4 * 8);
        h2 av[4];
#pragma unroll
        for (int i = 0; i < 4; ++i) { av[i][0] = a1[2 * i]; av[i][1] = a1[2 * i + 1]; }
#pragma unroll
        for (int j = 0; j < 3; ++j) {
            const f16* row = p2 + (size_t)j * 136 * 128 + c4 * 8;
#pragma unroll
            for (int d = 0; d < 9; ++d) {
                const f16x8 b2 = *(const f16x8*)(row + (size_t)d * 128);
#pragma unroll
                for (int i = 0; i < 4; ++i) {
                    h2 bv; bv[0] = b2[2 * i]; bv[1] = b2[2 * i + 1];
                    acc[j][d] = __builtin_amdgcn_fdot2(av[i], bv, acc[j][d], false);
                }
            }
        }
    }
#pragma unroll
    for (int j = 0; j < 3; ++j)
#pragma unroll
        for (int d = 0; d < 9; ++d)
            orow[(dy0 + j) * 9 + d] = (f16)(acc[j][d] * (1.f / 128.f));
}

// x1 fp32 NCHW -> IN0 NHWC ch0..127 AND PX1n channel-major layout
__global__ __launch_bounds__(256) void x1pack(const float* __restrict__ x1,
                                              f16* __restrict__ in0,
                                              f16* __restrict__ px1) {
    const int x = threadIdx.x & 127;
    const int y = blockIdx.x * 2 + (threadIdx.x >> 7);
    const int b = blockIdx.z;
    const float* p1 = x1 + (size_t)b * 128 * HW16K + y * 128 + x;
    f16* o = in0 + (((size_t)b * 130 + (y + 1)) * 130 + (x + 1)) * 224;
    f16* q = px1 + ((size_t)(b * 128 + y) * 128 + x) * 128;
    for (int cp = 0; cp < 64; ++cp) {
        const float a0 = p1[(2 * cp) * HW16K];
        const float a1 = p1[(2 * cp + 1) * HW16K];
        h2 v; v[0] = (f16)a0; v[1] = (f16)a1;
        *(h2*)(o + 2 * cp) = v;
        *(h2*)(q + 2 * cp) = v;
    }
}

// x2 fp32 NCHW -> PX2n padded channel-major layout (zeros in border)
__global__ __launch_bounds__(256) void x2pack(const float* __restrict__ x2,
                                              f16* __restrict__ px2) {
    const int cell = blockIdx.x * 256 + threadIdx.x;   // over 136x136
    if (cell >= 136 * 136) return;
    const int yp = cell / 136, xp = cell - yp * 136;
    const int b = blockIdx.z;
    f16* dst = px2 + ((size_t)(b * 136 + yp) * 136 + xp) * 128;
    const int yy = yp - 4, xx = xp - 4;
    if ((unsigned)yy < 128u && (unsigned)xx < 128u) {
        const float* p = x2 + (size_t)b * 128 * HW16K + yy * 128 + xx;
        for (int cp = 0; cp < 64; ++cp) {
            h2 v;
            v[0] = (f16)p[(2 * cp) * HW16K];
            v[1] = (f16)p[(2 * cp + 1) * HW16K];
            *(h2*)(dst + 2 * cp) = v;
        }
    } else {
        f16x8 z = {};
        for (int c = 0; c < 128; c += 8) *(f16x8*)(dst + c) = z;
    }
}

__global__ void zero_border(f16* buf, int Ye, int Xe, int Cs, int pad) {
    const int cell = blockIdx.x * 256 + threadIdx.x;
    const int total = Ye * Xe;
    if (cell >= total) return;
    const int yy = cell / Xe, xx = cell - yy * Xe;
    if (yy >= pad && yy < Ye - pad && xx >= pad && xx < Xe - pad) return;
    f16* p = buf + ((size_t)blockIdx.z * Ye * Xe + cell) * Cs;
    f16x8 z = {};
    for (int c = 0; c < Cs; c += 8) *(f16x8*)(p + c) = z;
}

// all 13 weight tensors: fp32 OIHW -> f16 [kt][tap][CoPad][16], zero-padded
struct PPA {
    const float* src[13];
    f16* dst[13];
    int Co[13], Ci[13], CoPad[13], CiPad[13];
};
__global__ void prepack_all(PPA a) {
    const int l = blockIdx.z;
    const int CoPad = a.CoPad[l], CiPad = a.CiPad[l];
    const int total = 9 * CoPad * CiPad;
    const int i = blockIdx.x * 256 + threadIdx.x;
    if (i >= total) return;
    const int k  = i / (CoPad * CiPad);
    const int r  = i - k * CoPad * CiPad;
    const int co = r / CiPad;
    const int ci = r - co * CiPad;
    f16 v = (f16)0.f;
    if (co < a.Co[l] && ci < a.Ci[l])
        v = (f16)a.src[l][((size_t)co * a.Ci[l] + ci) * 9 + k];
    const int kt = ci >> 4, cin = ci & 15;
    a.dst[l][(((size_t)kt * 9 + k) * CoPad + co) * 16 + cin] = v;
}

extern "C" void kernel_launch(void* const* d_in, const int* in_sizes, int n_in,
                              void* d_out, int out_size, void* d_ws, size_t ws_size,
                              hipStream_t stream) {
    const float* x1 = (const float*)d_in[0];
    const float* x2 = (const float*)d_in[1];
    const float* W[13]  = {(const float*)d_in[2],  (const float*)d_in[4],  (const float*)d_in[6],
                           (const float*)d_in[8],  (const float*)d_in[10], (const float*)d_in[12],
                           (const float*)d_in[14], (const float*)d_in[16], (const float*)d_in[18],
                           (const float*)d_in[20], (const float*)d_in[22], (const float*)d_in[24],
                           (const float*)d_in[26]};
    const float* Bs[13] = {(const float*)d_in[3],  (const float*)d_in[5],  (const float*)d_in[7],
                           (const float*)d_in[9],  (const float*)d_in[11], (const float*)d_in[13],
                           (const float*)d_in[15], (const float*)d_in[17], (const float*)d_in[19],
                           (const float*)d_in[21], (const float*)d_in[23], (const float*)d_in[25],
                           (const float*)d_in[27]};
    float* outp = (float*)d_out;

    // ---- workspace layout (bytes) ----
    char* ws = (char*)d_ws;
    f16* IN0 = (f16*)(ws);                       // [8][130][130][224] = 60,569,600 B
    f16* P   = (f16*)(ws + 60569600);            // [8][144][144][128] = 42,467,328 B
    f16* Q   = (f16*)(ws + 103036928);           // [8][160][160][128] = 52,428,800 B
    f16* CC  = (f16*)(ws + 155465728);           // [8][130][130][64]  = 17,305,600 B
    char* WPB = ws + 172771328;
    // PX1n/PX2n alias P/Q: consumed by corr BEFORE any conv writes P/Q.
    f16* PX1 = P;                                // 33,554,432 B < P
    f16* PX2 = Q;                                // 37,879,808 B < Q

    // per-layer: {Co, Ci, CoPad, CiPad}
    const int LC[13][4] = {
        {128, 209, 128, 224}, {128, 128, 128, 128}, {96, 128, 96, 128},
        {64, 96, 64, 96},     {32, 64, 32, 64},     {2, 32, 32, 32},
        {128, 34, 128, 64},   {128, 128, 128, 128}, {128, 128, 128, 128},
        {96, 128, 96, 128},   {64, 96, 64, 96},     {32, 64, 32, 64},
        {2, 32, 32, 32}};
    f16* wpp[13];
    PPA pa;
    {
        size_t off = 0;
        for (int l = 0; l < 13; ++l) {
            wpp[l] = (f16*)(WPB + off);
            off += (size_t)9 * LC[l][2] * LC[l][3] * 2;
            pa.src[l] = W[l]; pa.dst[l] = wpp[l];
            pa.Co[l] = LC[l][0]; pa.Ci[l] = LC[l][1];
            pa.CoPad[l] = LC[l][2]; pa.CiPad[l] = LC[l][3];
        }
    }

    const dim3 blk(256, 1, 1);
    const dim3 blk512(512, 1, 1);

    // weights (single fused launch) + borders of non-aliased buffers
    prepack_all<<<dim3(1008, 1, 13), blk, 0, stream>>>(pa);
    zero_border<<<dim3(67, 1, 8), blk, 0, stream>>>(IN0, 130, 130, 224, 1);
    zero_border<<<dim3(67, 1, 8), blk, 0, stream>>>(CC, 130, 130, 64, 1);

    // pack inputs + correlation
    x1pack<<<dim3(64, 1, 8), blk, 0, stream>>>(x1, IN0, PX1);
    x2pack<<<dim3(73, 1, 8), blk, 0, stream>>>(x2, PX2);
    corr_k<<<dim3(512, 3, 1), blk, 0, stream>>>(PX1, PX2, IN0);

    // PX1n/PX2n dead -> restore P/Q borders
    zero_border<<<dim3(81, 1, 8),  blk, 0, stream>>>(P, 144, 144, 128, 8);
    zero_border<<<dim3(100, 1, 8), blk, 0, stream>>>(Q, 160, 160, 128, 16);

    // ---- flow estimator ----
    conv_mfma<1, 2, 2, 0><<<dim3(512, 1, 1), blk512, 0, stream>>>(IN0, 130, 130, 224, 1, wpp[0], Bs[0],
                                                  P, 144, 144, 128, 8, 0, nullptr, 14, 128);
    conv_mfma<1, 2, 2, 0><<<dim3(512, 1, 1), blk512, 0, stream>>>(P, 144, 144, 128, 8, wpp[1], Bs[1],
                                                  Q, 160, 160, 128, 16, 0, nullptr, 8, 128);
    conv_mfma<1, 1, 3, 0><<<dim3(512, 1, 1), blk512, 0, stream>>>(Q, 160, 160, 128, 16, wpp[2], Bs[2],
                                                  P, 144, 144, 128, 8, 0, nullptr, 8, 96);
    conv_mfma<1, 1, 2, 0><<<dim3(512, 1, 1), blk512, 0, stream>>>(P, 144, 144, 128, 8, wpp[3], Bs[3],
                                                  Q, 160, 160, 128, 16, 0, nullptr, 6, 64);
    conv_mfma<1, 1, 1, 0><<<dim3(512, 1, 1), blk512, 0, stream>>>(Q, 160, 160, 128, 16, wpp[4], Bs[4],
                                                  CC, 130, 130, 64, 1, 0, nullptr, 4, 32);
    // flow head: reads CC ch0..31, writes d_out fp32 + CC ch32/33
    conv_mfma<1, 1, 1, 1><<<dim3(512, 1, 1), blk512, 0, stream>>>(CC, 130, 130, 64, 1, wpp[5], Bs[5],
                                                  CC, 130, 130, 64, 1, 32, outp, 2, 32);
    // ---- context network ----
    conv_mfma<1, 2, 2, 0><<<dim3(512, 1, 1), blk512, 0, stream>>>(CC, 130, 130, 64, 1, wpp[6], Bs[6],
                                                  P, 144, 144, 128, 8, 0, nullptr, 4, 128);
    conv_mfma<2, 2, 2, 0><<<dim3(512, 1, 1), blk512, 0, stream>>>(P, 144, 144, 128, 8, wpp[7], Bs[7],
                                                  Q, 160, 160, 128, 16, 0, nullptr, 8, 128);
    conv_mfma<4, 2, 2, 0><<<dim3(512, 1, 1), blk512, 0, stream>>>(Q, 160, 160, 128, 16, wpp[8], Bs[8],
                                                  P, 144, 144, 128, 8, 0, nullptr, 8, 128);
    conv_mfma<8, 1, 3, 0><<<dim3(512, 1, 1), blk512, 0, stream>>>(P, 144, 144, 128, 8, wpp[9], Bs[9],
                                                  Q, 160, 160, 128, 16, 0, nullptr, 8, 96);
    conv_mfma<16, 1, 2, 0><<<dim3(512, 1, 1), blk512, 0, stream>>>(Q, 160, 160, 128, 16, wpp[10], Bs[10],
                                                   P, 144, 144, 128, 8, 0, nullptr, 6, 64);
    conv_mfma<1, 1, 1, 0><<<dim3(512, 1, 1), blk512, 0, stream>>>(P, 144, 144, 128, 8, wpp[11], Bs[11],
                                                  Q, 160, 160, 128, 16, 0, nullptr, 4, 32);
    // final: 32->2, leaky, += flo (d_out)
    conv_mfma<1, 1, 1, 2><<<dim3(512, 1, 1), blk512, 0, stream>>>(Q, 160, 160, 128, 16, wpp[12], Bs[12],
                                                  nullptr, 0, 0, 0, 0, 0, outp, 2, 32);
}

// Round 13
// 752.356 us; speedup vs baseline: 1.5293x; 1.5293x over previous
//
#include <hip/hip_runtime.h>
#include <hip/hip_bf16.h>

typedef _Float16 f16;
typedef __attribute__((ext_vector_type(2)))  _Float16 h2;
typedef __attribute__((ext_vector_type(8)))  _Float16 f16x8;
typedef __attribute__((ext_vector_type(4)))  _Float16 f16x4;
typedef __attribute__((ext_vector_type(16))) float    f32x16;

#define HW16K 16384

__device__ __forceinline__ void gld16(const void* g, void* l) {
    __builtin_amdgcn_global_load_lds((const __attribute__((address_space(1))) void*)g,
                                     (__attribute__((address_space(3))) void*)l, 16, 0, 0);
}

// ---------------------------------------------------------------------------
// Implicit-GEMM 3x3 conv via v_mfma_f32_32x32x16_f16.  (r11 champion, frozen)
// ---------------------------------------------------------------------------
template <int DIL, int PXW, int MFW, int MODE>
__global__ __launch_bounds__(512, 4) void conv_mfma(
    const f16* __restrict__ in, int inYe, int inXe, int inCs, int inPad,
    const f16* __restrict__ wp, const float* __restrict__ bias,
    f16* __restrict__ out, int outYe, int outXe, int outCs, int outPad, int outCoOff,
    float* __restrict__ dout,
    int Ci16, int CoPad)
{
    constexpr int Wext = 128 + 2 * DIL;
    constexpr int NR   = (DIL == 1) ? 4 : 6;
    constexpr int CH   = NR * Wext * 2;        // 16B chunks per K-tile
    constexpr int CHB  = CH * 16;
    constexpr int TI   = (CH + 511) / 512;
    __shared__ __align__(16) char smem[2 * CHB];

    const int tid  = threadIdx.x;
    const int lane = tid & 63;
    const int wv   = tid >> 6;
    const int col  = lane & 31;
    const int hi   = lane >> 5;
    const int t    = wv >> 2;                  // output row within block
    const int wq   = wv & 3;
    constexpr int CPW = PXW;                   // co-slots per row-group
    const int pp   = wq / CPW;                 // px-group index
    const int c    = wq % CPW;                 // co-slot index
    const int cb0  = blockIdx.y * (32 * PXW * MFW);

    const int g  = blockIdx.x;                 // XCD-swizzled (b, ychunk)
    const int n  = (g & 7) * 64 + (g >> 3);
    const int b  = n >> 6;
    const int y0 = (n & 63) * 2;

    const f16* inb = in + (size_t)b * inYe * inXe * inCs;

    auto stage = [&](int kt, int bufi) {
        const int ci0 = kt * 16;
        char* sb = smem + bufi * CHB;
#pragma unroll
        for (int i = 0; i < TI; ++i) {
            int cc = i * 512 + tid;
            if (cc < CH) {
                int r   = cc / (Wext * 2);
                int rem = cc - r * (Wext * 2);
                int px = rem >> 1, half = rem & 1;
                int yin = (DIL == 1) ? (y0 - 1 + r)
                                     : (y0 + (r & 1) + ((r >> 1) - 1) * DIL);
                const f16* src = inb
                    + ((size_t)(yin + inPad) * inXe + (inPad - DIL + px)) * inCs
                    + ci0 + half * 8;
                gld16(src, sb + cc * 16);
            }
        }
    };

    f32x16 acc[PXW][MFW] = {};

    stage(0, 0);
    __syncthreads();
    for (int kt = 0; kt < Ci16; ++kt) {
        if (kt + 1 < Ci16) stage(kt + 1, (kt + 1) & 1);
        const char* sb = smem + (kt & 1) * CHB;
        const f16* wkt = wp + (size_t)kt * 9 * CoPad * 16 + hi * 8;

        if constexpr (MFW == 1) {
            f16x8 wfr[9];
#pragma unroll
            for (int k9 = 0; k9 < 9; ++k9)
                wfr[k9] = *(const f16x8*)(wkt + (size_t)k9 * CoPad * 16 +
                                          (cb0 + 32 * c + col) * 16);
#pragma unroll
            for (int ky = 0; ky < 3; ++ky) {
#pragma unroll
                for (int kx = 0; kx < 3; ++kx) {
                    const int rrow = (DIL == 1) ? (t + ky) : (ky * 2 + t);
#pragma unroll
                    for (int p = 0; p < PXW; ++p) {
                        const f16x8 bfrag = *(const f16x8*)(sb +
                            ((rrow * Wext + 32 * (PXW * pp + p) + col + kx * DIL) * 32 + hi * 16));
                        acc[p][0] = __builtin_amdgcn_mfma_f32_32x32x16_f16(
                            wfr[ky * 3 + kx], bfrag, acc[p][0], 0, 0, 0);
                    }
                }
            }
        } else {
#pragma unroll
            for (int ky = 0; ky < 3; ++ky) {
#pragma unroll
                for (int kx = 0; kx < 3; ++kx) {
                    const int rrow = (DIL == 1) ? (t + ky) : (ky * 2 + t);
                    f16x8 bfr[PXW];
#pragma unroll
                    for (int p = 0; p < PXW; ++p)
                        bfr[p] = *(const f16x8*)(sb +
                            ((rrow * Wext + 32 * (PXW * pp + p) + col + kx * DIL) * 32 + hi * 16));
                    const f16* wtap = wkt + (size_t)(ky * 3 + kx) * CoPad * 16;
#pragma unroll
                    for (int m = 0; m < MFW; ++m) {
                        const f16x8 afrag =
                            *(const f16x8*)(wtap + (cb0 + 32 * (c * MFW + m) + col) * 16);
#pragma unroll
                        for (int p = 0; p < PXW; ++p)
                            acc[p][m] = __builtin_amdgcn_mfma_f32_32x32x16_f16(
                                afrag, bfr[p], acc[p][m], 0, 0, 0);
                    }
                }
            }
        }
        __syncthreads();
    }

    // ---- epilogue ----
    const int y = y0 + t;
    if constexpr (MODE == 0) {
#pragma unroll
        for (int p = 0; p < PXW; ++p) {
            const int x = 32 * (PXW * pp + p) + col;
            const size_t pixbase =
                (((size_t)b * outYe + (y + outPad)) * outXe + (outPad + x)) * outCs + outCoOff;
#pragma unroll
            for (int m = 0; m < MFW; ++m) {
#pragma unroll
                for (int eq = 0; eq < 4; ++eq) {
                    const int co = cb0 + 32 * (c * MFW + m) + 8 * eq + 4 * hi;
                    f16x4 h;
#pragma unroll
                    for (int s = 0; s < 4; ++s) {
                        float v = acc[p][m][4 * eq + s] + bias[co + s];
                        v = (v >= 0.f) ? v : 0.1f * v;
                        h[s] = (f16)v;
                    }
                    *(f16x4*)(out + pixbase + co) = h;
                }
            }
        }
    } else {
        if (hi == 0) {
            const int x = 32 * pp + col;
#pragma unroll
            for (int s = 0; s < 2; ++s) {
                float v = acc[0][0][s] + bias[s];
                const size_t oi = (((size_t)b * 2 + s) * 128 + y) * 128 + x;
                if constexpr (MODE == 1) {
                    dout[oi] = v;
                    const size_t pixbase =
                        (((size_t)b * outYe + (y + outPad)) * outXe + (outPad + x)) * outCs + outCoOff;
                    out[pixbase + s] = (f16)v;
                } else {
                    v = (v >= 0.f) ? v : 0.1f * v;
                    dout[oi] += v;
                }
            }
        }
    }
}

// ---------------------------------------------------------------------------
// Correlation (r11-proven form + dy-split 9): channel-pair f16 layouts,
// v_dot2_f32_f16, SCALAR 4B loads, x = lane dim (coalesced).
// PX1: [b][64][128][128][2]   PX2: [b][64][136][136][2] (4-px zero border)
// One dy per block (blockIdx.y in 0..8) -> 4608 blocks, 2.25x oversubscribed
// for HBM-concurrency. Writes f16 into IN0 channels 128..208.
// ---------------------------------------------------------------------------
__global__ __launch_bounds__(256) void corr_k(const h2* __restrict__ px1,
                                              const h2* __restrict__ px2,
                                              f16* __restrict__ in0) {
    const int g = blockIdx.x;                  // bijective XCD swizzle
    const int n = (g & 7) * 64 + (g >> 3);
    const int b = n >> 6;
    const int x = threadIdx.x & 127;
    const int y = (n & 63) * 2 + (threadIdx.x >> 7);
    const int dy = blockIdx.y;

    const h2* p1  = px1 + (size_t)b * 64 * HW16K + y * 128 + x;
    const h2* p2r = px2 + (size_t)b * 64 * 18496 + (size_t)(y + dy) * 136 + x;
    f16* orow = in0 + (((size_t)b * 130 + (y + 1)) * 130 + (x + 1)) * 224 + 128;

    float acc[9] = {};
    for (int cp = 0; cp < 64; ++cp) {
        const h2 v1 = p1[(size_t)cp * HW16K];
        const h2* row = p2r + (size_t)cp * 18496;
#pragma unroll
        for (int d = 0; d < 9; ++d)
            acc[d] = __builtin_amdgcn_fdot2(v1, row[d], acc[d], false);
    }
#pragma unroll
    for (int d = 0; d < 9; ++d)
        orow[dy * 9 + d] = (f16)(acc[d] * (1.f / 128.f));
}

// x1 fp32 NCHW -> IN0 NHWC ch0..127 AND PX1 channel-pair layout
__global__ __launch_bounds__(256) void x1pack(const float* __restrict__ x1,
                                              f16* __restrict__ in0,
                                              h2* __restrict__ px1) {
    const int x = threadIdx.x & 127;
    const int y = blockIdx.x * 2 + (threadIdx.x >> 7);
    const int b = blockIdx.z;
    const float* p1 = x1 + (size_t)b * 128 * HW16K + y * 128 + x;
    f16* o = in0 + (((size_t)b * 130 + (y + 1)) * 130 + (x + 1)) * 224;
    h2* q = px1 + (size_t)b * 64 * HW16K + y * 128 + x;
    for (int cp = 0; cp < 64; ++cp) {
        const float a0 = p1[(2 * cp) * HW16K];
        const float a1 = p1[(2 * cp + 1) * HW16K];
        h2 v; v[0] = (f16)a0; v[1] = (f16)a1;
        q[(size_t)cp * HW16K] = v;
        *(h2*)(o + 2 * cp) = v;
    }
}

// x2 fp32 NCHW -> PX2 padded channel-pair layout (writes zeros in border)
__global__ __launch_bounds__(256) void x2pack(const float* __restrict__ x2,
                                              h2* __restrict__ px2) {
    const int cell = blockIdx.x * 256 + threadIdx.x;   // over 136x136
    if (cell >= 136 * 136) return;
    const int yp = cell / 136, xp = cell - yp * 136;
    const int cp = blockIdx.y, b = blockIdx.z;
    h2 v; v[0] = (f16)0.f; v[1] = (f16)0.f;
    const int yy = yp - 4, xx = xp - 4;
    if ((unsigned)yy < 128u && (unsigned)xx < 128u) {
        const float* p = x2 + (size_t)b * 128 * HW16K + (2 * cp) * HW16K + yy * 128 + xx;
        v[0] = (f16)p[0];
        v[1] = (f16)p[HW16K];
    }
    px2[((size_t)(b * 64 + cp) * 136 + yp) * 136 + xp] = v;
}

__global__ void zero_border(f16* buf, int Ye, int Xe, int Cs, int pad) {
    const int cell = blockIdx.x * 256 + threadIdx.x;
    const int total = Ye * Xe;
    if (cell >= total) return;
    const int yy = cell / Xe, xx = cell - yy * Xe;
    if (yy >= pad && yy < Ye - pad && xx >= pad && xx < Xe - pad) return;
    f16* p = buf + ((size_t)blockIdx.z * Ye * Xe + cell) * Cs;
    f16x8 z = {};
    for (int c = 0; c < Cs; c += 8) *(f16x8*)(p + c) = z;
}

// all 13 weight tensors: fp32 OIHW -> f16 [kt][tap][CoPad][16], zero-padded
struct PPA {
    const float* src[13];
    f16* dst[13];
    int Co[13], Ci[13], CoPad[13], CiPad[13];
};
__global__ void prepack_all(PPA a) {
    const int l = blockIdx.z;
    const int CoPad = a.CoPad[l], CiPad = a.CiPad[l];
    const int total = 9 * CoPad * CiPad;
    const int i = blockIdx.x * 256 + threadIdx.x;
    if (i >= total) return;
    const int k  = i / (CoPad * CiPad);
    const int r  = i - k * CoPad * CiPad;
    const int co = r / CiPad;
    const int ci = r - co * CiPad;
    f16 v = (f16)0.f;
    if (co < a.Co[l] && ci < a.Ci[l])
        v = (f16)a.src[l][((size_t)co * a.Ci[l] + ci) * 9 + k];
    const int kt = ci >> 4, cin = ci & 15;
    a.dst[l][(((size_t)kt * 9 + k) * CoPad + co) * 16 + cin] = v;
}

extern "C" void kernel_launch(void* const* d_in, const int* in_sizes, int n_in,
                              void* d_out, int out_size, void* d_ws, size_t ws_size,
                              hipStream_t stream) {
    const float* x1 = (const float*)d_in[0];
    const float* x2 = (const float*)d_in[1];
    const float* W[13]  = {(const float*)d_in[2],  (const float*)d_in[4],  (const float*)d_in[6],
                           (const float*)d_in[8],  (const float*)d_in[10], (const float*)d_in[12],
                           (const float*)d_in[14], (const float*)d_in[16], (const float*)d_in[18],
                           (const float*)d_in[20], (const float*)d_in[22], (const float*)d_in[24],
                           (const float*)d_in[26]};
    const float* Bs[13] = {(const float*)d_in[3],  (const float*)d_in[5],  (const float*)d_in[7],
                           (const float*)d_in[9],  (const float*)d_in[11], (const float*)d_in[13],
                           (const float*)d_in[15], (const float*)d_in[17], (const float*)d_in[19],
                           (const float*)d_in[21], (const float*)d_in[23], (const float*)d_in[25],
                           (const float*)d_in[27]};
    float* outp = (float*)d_out;

    // ---- workspace layout (bytes) ----
    char* ws = (char*)d_ws;
    f16* IN0 = (f16*)(ws);                       // [8][130][130][224] = 60,569,600 B
    f16* P   = (f16*)(ws + 60569600);            // [8][144][144][128] = 42,467,328 B
    f16* Q   = (f16*)(ws + 103036928);           // [8][160][160][128] = 52,428,800 B
    f16* CC  = (f16*)(ws + 155465728);           // [8][130][130][64]  = 17,305,600 B
    char* WPB = ws + 172771328;
    // PX1/PX2 alias P/Q: consumed by corr BEFORE any conv writes P/Q.
    h2* PX1 = (h2*)P;
    h2* PX2 = (h2*)Q;

    // per-layer: {Co, Ci, CoPad, CiPad}
    const int LC[13][4] = {
        {128, 209, 128, 224}, {128, 128, 128, 128}, {96, 128, 96, 128},
        {64, 96, 64, 96},     {32, 64, 32, 64},     {2, 32, 32, 32},
        {128, 34, 128, 64},   {128, 128, 128, 128}, {128, 128, 128, 128},
        {96, 128, 96, 128},   {64, 96, 64, 96},     {32, 64, 32, 64},
        {2, 32, 32, 32}};
    f16* wpp[13];
    PPA pa;
    {
        size_t off = 0;
        for (int l = 0; l < 13; ++l) {
            wpp[l] = (f16*)(WPB + off);
            off += (size_t)9 * LC[l][2] * LC[l][3] * 2;
            pa.src[l] = W[l]; pa.dst[l] = wpp[l];
            pa.Co[l] = LC[l][0]; pa.Ci[l] = LC[l][1];
            pa.CoPad[l] = LC[l][2]; pa.CiPad[l] = LC[l][3];
        }
    }

    const dim3 blk(256, 1, 1);
    const dim3 blk512(512, 1, 1);

    // weights (single fused launch) + borders of non-aliased buffers
    prepack_all<<<dim3(1008, 1, 13), blk, 0, stream>>>(pa);
    zero_border<<<dim3(67, 1, 8), blk, 0, stream>>>(IN0, 130, 130, 224, 1);
    zero_border<<<dim3(67, 1, 8), blk, 0, stream>>>(CC, 130, 130, 64, 1);

    // pack inputs + correlation
    x1pack<<<dim3(64, 1, 8), blk, 0, stream>>>(x1, IN0, PX1);
    x2pack<<<dim3(73, 64, 8), blk, 0, stream>>>(x2, PX2);
    corr_k<<<dim3(512, 9, 1), blk, 0, stream>>>(PX1, PX2, IN0);

    // PX1/PX2 dead -> restore P/Q borders
    zero_border<<<dim3(81, 1, 8),  blk, 0, stream>>>(P, 144, 144, 128, 8);
    zero_border<<<dim3(100, 1, 8), blk, 0, stream>>>(Q, 160, 160, 128, 16);

    // ---- flow estimator ----
    conv_mfma<1, 2, 2, 0><<<dim3(512, 1, 1), blk512, 0, stream>>>(IN0, 130, 130, 224, 1, wpp[0], Bs[0],
                                                  P, 144, 144, 128, 8, 0, nullptr, 14, 128);
    conv_mfma<1, 2, 2, 0><<<dim3(512, 1, 1), blk512, 0, stream>>>(P, 144, 144, 128, 8, wpp[1], Bs[1],
                                                  Q, 160, 160, 128, 16, 0, nullptr, 8, 128);
    conv_mfma<1, 1, 3, 0><<<dim3(512, 1, 1), blk512, 0, stream>>>(Q, 160, 160, 128, 16, wpp[2], Bs[2],
                                                  P, 144, 144, 128, 8, 0, nullptr, 8, 96);
    conv_mfma<1, 1, 2, 0><<<dim3(512, 1, 1), blk512, 0, stream>>>(P, 144, 144, 128, 8, wpp[3], Bs[3],
                                                  Q, 160, 160, 128, 16, 0, nullptr, 6, 64);
    conv_mfma<1, 1, 1, 0><<<dim3(512, 1, 1), blk512, 0, stream>>>(Q, 160, 160, 128, 16, wpp[4], Bs[4],
                                                  CC, 130, 130, 64, 1, 0, nullptr, 4, 32);
    // flow head: reads CC ch0..31, writes d_out fp32 + CC ch32/33
    conv_mfma<1, 1, 1, 1><<<dim3(512, 1, 1), blk512, 0, stream>>>(CC, 130, 130, 64, 1, wpp[5], Bs[5],
                                                  CC, 130, 130, 64, 1, 32, outp, 2, 32);
    // ---- context network ----
    conv_mfma<1, 2, 2, 0><<<dim3(512, 1, 1), blk512, 0, stream>>>(CC, 130, 130, 64, 1, wpp[6], Bs[6],
                                                  P, 144, 144, 128, 8, 0, nullptr, 4, 128);
    conv_mfma<2, 2, 2, 0><<<dim3(512, 1, 1), blk512, 0, stream>>>(P, 144, 144, 128, 8, wpp[7], Bs[7],
                                                  Q, 160, 160, 128, 16, 0, nullptr, 8, 128);
    conv_mfma<4, 2, 2, 0><<<dim3(512, 1, 1), blk512, 0, stream>>>(Q, 160, 160, 128, 16, wpp[8], Bs[8],
                                                  P, 144, 144, 128, 8, 0, nullptr, 8, 128);
    conv_mfma<8, 1, 3, 0><<<dim3(512, 1, 1), blk512, 0, stream>>>(P, 144, 144, 128, 8, wpp[9], Bs[9],
                                                  Q, 160, 160, 128, 16, 0, nullptr, 8, 96);
    conv_mfma<16, 1, 2, 0><<<dim3(512, 1, 1), blk512, 0, stream>>>(Q, 160, 160, 128, 16, wpp[10], Bs[10],
                                                   P, 144, 144, 128, 8, 0, nullptr, 6, 64);
    conv_mfma<1, 1, 1, 0><<<dim3(512, 1, 1), blk512, 0, stream>>>(P, 144, 144, 128, 8, wpp[11], Bs[11],
                                                  Q, 160, 160, 128, 16, 0, nullptr, 4, 32);
    // final: 32->2, leaky, += flo (d_out)
    conv_mfma<1, 1, 1, 2><<<dim3(512, 1, 1), blk512, 0, stream>>>(Q, 160, 160, 128, 16, wpp[12], Bs[12],
                                                  nullptr, 0, 0, 0, 0, 0, outp, 2, 32);
}

// Round 14
// 729.655 us; speedup vs baseline: 1.5768x; 1.0311x over previous
//
#include <hip/hip_runtime.h>
#include <hip/hip_bf16.h>

typedef _Float16 f16;
typedef __attribute__((ext_vector_type(2)))  _Float16 h2;
typedef __attribute__((ext_vector_type(8)))  _Float16 f16x8;
typedef __attribute__((ext_vector_type(4)))  _Float16 f16x4;
typedef __attribute__((ext_vector_type(16))) float    f32x16;

#define HW16K 16384

__device__ __forceinline__ void gld16(const void* g, void* l) {
    __builtin_amdgcn_global_load_lds((const __attribute__((address_space(1))) void*)g,
                                     (__attribute__((address_space(3))) void*)l, 16, 0, 0);
}

// ---------------------------------------------------------------------------
// Implicit-GEMM 3x3 conv via v_mfma_f32_32x32x16_f16.  (r11 champion, frozen)
// ---------------------------------------------------------------------------
template <int DIL, int PXW, int MFW, int MODE>
__global__ __launch_bounds__(512, 4) void conv_mfma(
    const f16* __restrict__ in, int inYe, int inXe, int inCs, int inPad,
    const f16* __restrict__ wp, const float* __restrict__ bias,
    f16* __restrict__ out, int outYe, int outXe, int outCs, int outPad, int outCoOff,
    float* __restrict__ dout,
    int Ci16, int CoPad)
{
    constexpr int Wext = 128 + 2 * DIL;
    constexpr int NR   = (DIL == 1) ? 4 : 6;
    constexpr int CH   = NR * Wext * 2;        // 16B chunks per K-tile
    constexpr int CHB  = CH * 16;
    constexpr int TI   = (CH + 511) / 512;
    __shared__ __align__(16) char smem[2 * CHB];

    const int tid  = threadIdx.x;
    const int lane = tid & 63;
    const int wv   = tid >> 6;
    const int col  = lane & 31;
    const int hi   = lane >> 5;
    const int t    = wv >> 2;                  // output row within block
    const int wq   = wv & 3;
    constexpr int CPW = PXW;                   // co-slots per row-group
    const int pp   = wq / CPW;                 // px-group index
    const int c    = wq % CPW;                 // co-slot index
    const int cb0  = blockIdx.y * (32 * PXW * MFW);

    const int g  = blockIdx.x;                 // XCD-swizzled (b, ychunk)
    const int n  = (g & 7) * 64 + (g >> 3);
    const int b  = n >> 6;
    const int y0 = (n & 63) * 2;

    const f16* inb = in + (size_t)b * inYe * inXe * inCs;

    auto stage = [&](int kt, int bufi) {
        const int ci0 = kt * 16;
        char* sb = smem + bufi * CHB;
#pragma unroll
        for (int i = 0; i < TI; ++i) {
            int cc = i * 512 + tid;
            if (cc < CH) {
                int r   = cc / (Wext * 2);
                int rem = cc - r * (Wext * 2);
                int px = rem >> 1, half = rem & 1;
                int yin = (DIL == 1) ? (y0 - 1 + r)
                                     : (y0 + (r & 1) + ((r >> 1) - 1) * DIL);
                const f16* src = inb
                    + ((size_t)(yin + inPad) * inXe + (inPad - DIL + px)) * inCs
                    + ci0 + half * 8;
                gld16(src, sb + cc * 16);
            }
        }
    };

    f32x16 acc[PXW][MFW] = {};

    stage(0, 0);
    __syncthreads();
    for (int kt = 0; kt < Ci16; ++kt) {
        if (kt + 1 < Ci16) stage(kt + 1, (kt + 1) & 1);
        const char* sb = smem + (kt & 1) * CHB;
        const f16* wkt = wp + (size_t)kt * 9 * CoPad * 16 + hi * 8;

        if constexpr (MFW == 1) {
            f16x8 wfr[9];
#pragma unroll
            for (int k9 = 0; k9 < 9; ++k9)
                wfr[k9] = *(const f16x8*)(wkt + (size_t)k9 * CoPad * 16 +
                                          (cb0 + 32 * c + col) * 16);
#pragma unroll
            for (int ky = 0; ky < 3; ++ky) {
#pragma unroll
                for (int kx = 0; kx < 3; ++kx) {
                    const int rrow = (DIL == 1) ? (t + ky) : (ky * 2 + t);
#pragma unroll
                    for (int p = 0; p < PXW; ++p) {
                        const f16x8 bfrag = *(const f16x8*)(sb +
                            ((rrow * Wext + 32 * (PXW * pp + p) + col + kx * DIL) * 32 + hi * 16));
                        acc[p][0] = __builtin_amdgcn_mfma_f32_32x32x16_f16(
                            wfr[ky * 3 + kx], bfrag, acc[p][0], 0, 0, 0);
                    }
                }
            }
        } else {
#pragma unroll
            for (int ky = 0; ky < 3; ++ky) {
#pragma unroll
                for (int kx = 0; kx < 3; ++kx) {
                    const int rrow = (DIL == 1) ? (t + ky) : (ky * 2 + t);
                    f16x8 bfr[PXW];
#pragma unroll
                    for (int p = 0; p < PXW; ++p)
                        bfr[p] = *(const f16x8*)(sb +
                            ((rrow * Wext + 32 * (PXW * pp + p) + col + kx * DIL) * 32 + hi * 16));
                    const f16* wtap = wkt + (size_t)(ky * 3 + kx) * CoPad * 16;
#pragma unroll
                    for (int m = 0; m < MFW; ++m) {
                        const f16x8 afrag =
                            *(const f16x8*)(wtap + (cb0 + 32 * (c * MFW + m) + col) * 16);
#pragma unroll
                        for (int p = 0; p < PXW; ++p)
                            acc[p][m] = __builtin_amdgcn_mfma_f32_32x32x16_f16(
                                afrag, bfr[p], acc[p][m], 0, 0, 0);
                    }
                }
            }
        }
        __syncthreads();
    }

    // ---- epilogue ----
    const int y = y0 + t;
    if constexpr (MODE == 0) {
#pragma unroll
        for (int p = 0; p < PXW; ++p) {
            const int x = 32 * (PXW * pp + p) + col;
            const size_t pixbase =
                (((size_t)b * outYe + (y + outPad)) * outXe + (outPad + x)) * outCs + outCoOff;
#pragma unroll
            for (int m = 0; m < MFW; ++m) {
#pragma unroll
                for (int eq = 0; eq < 4; ++eq) {
                    const int co = cb0 + 32 * (c * MFW + m) + 8 * eq + 4 * hi;
                    f16x4 h;
#pragma unroll
                    for (int s = 0; s < 4; ++s) {
                        float v = acc[p][m][4 * eq + s] + bias[co + s];
                        v = (v >= 0.f) ? v : 0.1f * v;
                        h[s] = (f16)v;
                    }
                    *(f16x4*)(out + pixbase + co) = h;
                }
            }
        }
    } else {
        if (hi == 0) {
            const int x = 32 * pp + col;
#pragma unroll
            for (int s = 0; s < 2; ++s) {
                float v = acc[0][0][s] + bias[s];
                const size_t oi = (((size_t)b * 2 + s) * 128 + y) * 128 + x;
                if constexpr (MODE == 1) {
                    dout[oi] = v;
                    const size_t pixbase =
                        (((size_t)b * outYe + (y + outPad)) * outXe + (outPad + x)) * outCs + outCoOff;
                    out[pixbase + s] = (f16)v;
                } else {
                    v = (v >= 0.f) ? v : 0.1f * v;
                    dout[oi] += v;
                }
            }
        }
    }
}

// ---------------------------------------------------------------------------
// Correlation v5: all 9 dy in ONE block (acc[9][9], ILP-driven latency hiding).
// Channel-pair layouts, v_dot2_f32_f16, scalar 4B loads, x = lane dim.
// PX1: [b][64][128][128][2]   PX2: [b][64][136][136][2] (4-px zero border)
// Per cp-iter: 1 x1 load + 81 INDEPENDENT x2 loads + 81 dot2 -> deep load
// window per wave; PX1 read exactly once (minimal L2-miss traffic).
// Grid 512 (XCD-bijective, b = g&7). __launch_bounds__(256,2): 256-VGPR
// budget for the 81 accumulators (statically indexed, no spill).
// ---------------------------------------------------------------------------
__global__ __launch_bounds__(256, 2) void corr_k(const h2* __restrict__ px1,
                                                 const h2* __restrict__ px2,
                                                 f16* __restrict__ in0) {
    const int g = blockIdx.x;                  // bijective XCD swizzle
    const int n = (g & 7) * 64 + (g >> 3);
    const int b = n >> 6;
    const int x = threadIdx.x & 127;
    const int y = (n & 63) * 2 + (threadIdx.x >> 7);

    const h2* p1  = px1 + (size_t)b * 64 * HW16K + y * 128 + x;
    const h2* p2b = px2 + (size_t)b * 64 * 18496 + (size_t)y * 136 + x;
    f16* orow = in0 + (((size_t)b * 130 + (y + 1)) * 130 + (x + 1)) * 224 + 128;

    float acc[9][9] = {};
    for (int cp = 0; cp < 64; ++cp) {
        const h2 v1 = p1[(size_t)cp * HW16K];
        const h2* base = p2b + (size_t)cp * 18496;
#pragma unroll
        for (int j = 0; j < 9; ++j) {
            const h2* row = base + j * 136;
#pragma unroll
            for (int d = 0; d < 9; ++d)
                acc[j][d] = __builtin_amdgcn_fdot2(v1, row[d], acc[j][d], false);
        }
    }
#pragma unroll
    for (int j = 0; j < 9; ++j)
#pragma unroll
        for (int d = 0; d < 9; ++d)
            orow[j * 9 + d] = (f16)(acc[j][d] * (1.f / 128.f));
}

// x1 fp32 NCHW -> IN0 NHWC ch0..127 AND PX1 channel-pair layout
__global__ __launch_bounds__(256) void x1pack(const float* __restrict__ x1,
                                              f16* __restrict__ in0,
                                              h2* __restrict__ px1) {
    const int x = threadIdx.x & 127;
    const int y = blockIdx.x * 2 + (threadIdx.x >> 7);
    const int b = blockIdx.z;
    const float* p1 = x1 + (size_t)b * 128 * HW16K + y * 128 + x;
    f16* o = in0 + (((size_t)b * 130 + (y + 1)) * 130 + (x + 1)) * 224;
    h2* q = px1 + (size_t)b * 64 * HW16K + y * 128 + x;
    for (int cp = 0; cp < 64; ++cp) {
        const float a0 = p1[(2 * cp) * HW16K];
        const float a1 = p1[(2 * cp + 1) * HW16K];
        h2 v; v[0] = (f16)a0; v[1] = (f16)a1;
        q[(size_t)cp * HW16K] = v;
        *(h2*)(o + 2 * cp) = v;
    }
}

// x2 fp32 NCHW -> PX2 padded channel-pair layout (writes zeros in border)
__global__ __launch_bounds__(256) void x2pack(const float* __restrict__ x2,
                                              h2* __restrict__ px2) {
    const int cell = blockIdx.x * 256 + threadIdx.x;   // over 136x136
    if (cell >= 136 * 136) return;
    const int yp = cell / 136, xp = cell - yp * 136;
    const int cp = blockIdx.y, b = blockIdx.z;
    h2 v; v[0] = (f16)0.f; v[1] = (f16)0.f;
    const int yy = yp - 4, xx = xp - 4;
    if ((unsigned)yy < 128u && (unsigned)xx < 128u) {
        const float* p = x2 + (size_t)b * 128 * HW16K + (2 * cp) * HW16K + yy * 128 + xx;
        v[0] = (f16)p[0];
        v[1] = (f16)p[HW16K];
    }
    px2[((size_t)(b * 64 + cp) * 136 + yp) * 136 + xp] = v;
}

__global__ void zero_border(f16* buf, int Ye, int Xe, int Cs, int pad) {
    const int cell = blockIdx.x * 256 + threadIdx.x;
    const int total = Ye * Xe;
    if (cell >= total) return;
    const int yy = cell / Xe, xx = cell - yy * Xe;
    if (yy >= pad && yy < Ye - pad && xx >= pad && xx < Xe - pad) return;
    f16* p = buf + ((size_t)blockIdx.z * Ye * Xe + cell) * Cs;
    f16x8 z = {};
    for (int c = 0; c < Cs; c += 8) *(f16x8*)(p + c) = z;
}

// all 13 weight tensors: fp32 OIHW -> f16 [kt][tap][CoPad][16], zero-padded
struct PPA {
    const float* src[13];
    f16* dst[13];
    int Co[13], Ci[13], CoPad[13], CiPad[13];
};
__global__ void prepack_all(PPA a) {
    const int l = blockIdx.z;
    const int CoPad = a.CoPad[l], CiPad = a.CiPad[l];
    const int total = 9 * CoPad * CiPad;
    const int i = blockIdx.x * 256 + threadIdx.x;
    if (i >= total) return;
    const int k  = i / (CoPad * CiPad);
    const int r  = i - k * CoPad * CiPad;
    const int co = r / CiPad;
    const int ci = r - co * CiPad;
    f16 v = (f16)0.f;
    if (co < a.Co[l] && ci < a.Ci[l])
        v = (f16)a.src[l][((size_t)co * a.Ci[l] + ci) * 9 + k];
    const int kt = ci >> 4, cin = ci & 15;
    a.dst[l][(((size_t)kt * 9 + k) * CoPad + co) * 16 + cin] = v;
}

extern "C" void kernel_launch(void* const* d_in, const int* in_sizes, int n_in,
                              void* d_out, int out_size, void* d_ws, size_t ws_size,
                              hipStream_t stream) {
    const float* x1 = (const float*)d_in[0];
    const float* x2 = (const float*)d_in[1];
    const float* W[13]  = {(const float*)d_in[2],  (const float*)d_in[4],  (const float*)d_in[6],
                           (const float*)d_in[8],  (const float*)d_in[10], (const float*)d_in[12],
                           (const float*)d_in[14], (const float*)d_in[16], (const float*)d_in[18],
                           (const float*)d_in[20], (const float*)d_in[22], (const float*)d_in[24],
                           (const float*)d_in[26]};
    const float* Bs[13] = {(const float*)d_in[3],  (const float*)d_in[5],  (const float*)d_in[7],
                           (const float*)d_in[9],  (const float*)d_in[11], (const float*)d_in[13],
                           (const float*)d_in[15], (const float*)d_in[17], (const float*)d_in[19],
                           (const float*)d_in[21], (const float*)d_in[23], (const float*)d_in[25],
                           (const float*)d_in[27]};
    float* outp = (float*)d_out;

    // ---- workspace layout (bytes) ----
    char* ws = (char*)d_ws;
    f16* IN0 = (f16*)(ws);                       // [8][130][130][224] = 60,569,600 B
    f16* P   = (f16*)(ws + 60569600);            // [8][144][144][128] = 42,467,328 B
    f16* Q   = (f16*)(ws + 103036928);           // [8][160][160][128] = 52,428,800 B
    f16* CC  = (f16*)(ws + 155465728);           // [8][130][130][64]  = 17,305,600 B
    char* WPB = ws + 172771328;
    // PX1/PX2 alias P/Q: consumed by corr BEFORE any conv writes P/Q.
    h2* PX1 = (h2*)P;
    h2* PX2 = (h2*)Q;

    // per-layer: {Co, Ci, CoPad, CiPad}
    const int LC[13][4] = {
        {128, 209, 128, 224}, {128, 128, 128, 128}, {96, 128, 96, 128},
        {64, 96, 64, 96},     {32, 64, 32, 64},     {2, 32, 32, 32},
        {128, 34, 128, 64},   {128, 128, 128, 128}, {128, 128, 128, 128},
        {96, 128, 96, 128},   {64, 96, 64, 96},     {32, 64, 32, 64},
        {2, 32, 32, 32}};
    f16* wpp[13];
    PPA pa;
    {
        size_t off = 0;
        for (int l = 0; l < 13; ++l) {
            wpp[l] = (f16*)(WPB + off);
            off += (size_t)9 * LC[l][2] * LC[l][3] * 2;
            pa.src[l] = W[l]; pa.dst[l] = wpp[l];
            pa.Co[l] = LC[l][0]; pa.Ci[l] = LC[l][1];
            pa.CoPad[l] = LC[l][2]; pa.CiPad[l] = LC[l][3];
        }
    }

    const dim3 blk(256, 1, 1);
    const dim3 blk512(512, 1, 1);

    // weights (single fused launch) + borders of non-aliased buffers
    prepack_all<<<dim3(1008, 1, 13), blk, 0, stream>>>(pa);
    zero_border<<<dim3(67, 1, 8), blk, 0, stream>>>(IN0, 130, 130, 224, 1);
    zero_border<<<dim3(67, 1, 8), blk, 0, stream>>>(CC, 130, 130, 64, 1);

    // pack inputs + correlation
    x1pack<<<dim3(64, 1, 8), blk, 0, stream>>>(x1, IN0, PX1);
    x2pack<<<dim3(73, 64, 8), blk, 0, stream>>>(x2, PX2);
    corr_k<<<dim3(512, 1, 1), blk, 0, stream>>>(PX1, PX2, IN0);

    // PX1/PX2 dead -> restore P/Q borders
    zero_border<<<dim3(81, 1, 8),  blk, 0, stream>>>(P, 144, 144, 128, 8);
    zero_border<<<dim3(100, 1, 8), blk, 0, stream>>>(Q, 160, 160, 128, 16);

    // ---- flow estimator ----
    conv_mfma<1, 2, 2, 0><<<dim3(512, 1, 1), blk512, 0, stream>>>(IN0, 130, 130, 224, 1, wpp[0], Bs[0],
                                                  P, 144, 144, 128, 8, 0, nullptr, 14, 128);
    conv_mfma<1, 2, 2, 0><<<dim3(512, 1, 1), blk512, 0, stream>>>(P, 144, 144, 128, 8, wpp[1], Bs[1],
                                                  Q, 160, 160, 128, 16, 0, nullptr, 8, 128);
    conv_mfma<1, 1, 3, 0><<<dim3(512, 1, 1), blk512, 0, stream>>>(Q, 160, 160, 128, 16, wpp[2], Bs[2],
                                                  P, 144, 144, 128, 8, 0, nullptr, 8, 96);
    conv_mfma<1, 1, 2, 0><<<dim3(512, 1, 1), blk512, 0, stream>>>(P, 144, 144, 128, 8, wpp[3], Bs[3],
                                                  Q, 160, 160, 128, 16, 0, nullptr, 6, 64);
    conv_mfma<1, 1, 1, 0><<<dim3(512, 1, 1), blk512, 0, stream>>>(Q, 160, 160, 128, 16, wpp[4], Bs[4],
                                                  CC, 130, 130, 64, 1, 0, nullptr, 4, 32);
    // flow head: reads CC ch0..31, writes d_out fp32 + CC ch32/33
    conv_mfma<1, 1, 1, 1><<<dim3(512, 1, 1), blk512, 0, stream>>>(CC, 130, 130, 64, 1, wpp[5], Bs[5],
                                                  CC, 130, 130, 64, 1, 32, outp, 2, 32);
    // ---- context network ----
    conv_mfma<1, 2, 2, 0><<<dim3(512, 1, 1), blk512, 0, stream>>>(CC, 130, 130, 64, 1, wpp[6], Bs[6],
                                                  P, 144, 144, 128, 8, 0, nullptr, 4, 128);
    conv_mfma<2, 2, 2, 0><<<dim3(512, 1, 1), blk512, 0, stream>>>(P, 144, 144, 128, 8, wpp[7], Bs[7],
                                                  Q, 160, 160, 128, 16, 0, nullptr, 8, 128);
    conv_mfma<4, 2, 2, 0><<<dim3(512, 1, 1), blk512, 0, stream>>>(Q, 160, 160, 128, 16, wpp[8], Bs[8],
                                                  P, 144, 144, 128, 8, 0, nullptr, 8, 128);
    conv_mfma<8, 1, 3, 0><<<dim3(512, 1, 1), blk512, 0, stream>>>(P, 144, 144, 128, 8, wpp[9], Bs[9],
                                                  Q, 160, 160, 128, 16, 0, nullptr, 8, 96);
    conv_mfma<16, 1, 2, 0><<<dim3(512, 1, 1), blk512, 0, stream>>>(Q, 160, 160, 128, 16, wpp[10], Bs[10],
                                                   P, 144, 144, 128, 8, 0, nullptr, 6, 64);
    conv_mfma<1, 1, 1, 0><<<dim3(512, 1, 1), blk512, 0, stream>>>(P, 144, 144, 128, 8, wpp[11], Bs[11],
                                                  Q, 160, 160, 128, 16, 0, nullptr, 4, 32);
    // final: 32->2, leaky, += flo (d_out)
    conv_mfma<1, 1, 1, 2><<<dim3(512, 1, 1), blk512, 0, stream>>>(Q, 160, 160, 128, 16, wpp[12], Bs[12],
                                                  nullptr, 0, 0, 0, 0, 0, outp, 2, 32);
}

// Round 15
// 613.405 us; speedup vs baseline: 1.8757x; 1.1895x over previous
//
#include <hip/hip_runtime.h>
#include <hip/hip_bf16.h>

typedef _Float16 f16;
typedef __attribute__((ext_vector_type(2)))  _Float16 h2;
typedef __attribute__((ext_vector_type(8)))  _Float16 f16x8;
typedef __attribute__((ext_vector_type(4)))  _Float16 f16x4;
typedef __attribute__((ext_vector_type(16))) float    f32x16;

#define HW16K 16384

__device__ __forceinline__ void gld16(const void* g, void* l) {
    __builtin_amdgcn_global_load_lds((const __attribute__((address_space(1))) void*)g,
                                     (__attribute__((address_space(3))) void*)l, 16, 0, 0);
}

// ---------------------------------------------------------------------------
// Implicit-GEMM 3x3 conv via v_mfma_f32_32x32x16_f16.
// ROUND 15: activations CHANNEL-16-TILED NHWC: [B][Ye][CiT][Xe][16ch] f16.
// One K-tile's row-window is CONTIGUOUS (Xe*32B/row) -> staging gld16 is
// fully linear (8 cachelines per wave-instr, was 32). LDS layout, chunk map,
// ds_read pattern and compute schedule are byte-identical to the r11/r14
// champion; only global address maps changed.
// Block 512 (8 waves) = 2 rows x 128 px x (32*PXW*MFW) co.
// ---------------------------------------------------------------------------
template <int DIL, int PXW, int MFW, int MODE>
__global__ __launch_bounds__(512, 4) void conv_mfma(
    const f16* __restrict__ in, int inYe, int inXe, int inCiT, int inPad,
    const f16* __restrict__ wp, const float* __restrict__ bias,
    f16* __restrict__ out, int outYe, int outXe, int outCoT, int outPad, int outCoOff,
    float* __restrict__ dout,
    int Ci16, int CoPad)
{
    constexpr int Wext = 128 + 2 * DIL;
    constexpr int NR   = (DIL == 1) ? 4 : 6;
    constexpr int CH   = NR * Wext * 2;        // 16B chunks per K-tile
    constexpr int CHB  = CH * 16;
    constexpr int TI   = (CH + 511) / 512;
    __shared__ __align__(16) char smem[2 * CHB];

    const int tid  = threadIdx.x;
    const int lane = tid & 63;
    const int wv   = tid >> 6;
    const int col  = lane & 31;
    const int hi   = lane >> 5;
    const int t    = wv >> 2;                  // output row within block
    const int wq   = wv & 3;
    constexpr int CPW = PXW;                   // co-slots per row-group
    const int pp   = wq / CPW;                 // px-group index
    const int c    = wq % CPW;                 // co-slot index
    const int cb0  = blockIdx.y * (32 * PXW * MFW);

    const int g  = blockIdx.x;                 // XCD-swizzled (b, ychunk)
    const int n  = (g & 7) * 64 + (g >> 3);
    const int b  = n >> 6;
    const int y0 = (n & 63) * 2;

    const f16* inb = in + (size_t)b * inYe * inCiT * inXe * 16;

    auto stage = [&](int kt, int bufi) {
        char* sb = smem + bufi * CHB;
#pragma unroll
        for (int i = 0; i < TI; ++i) {
            int cc = i * 512 + tid;
            if (cc < CH) {
                int r   = cc / (Wext * 2);
                int rem = cc - r * (Wext * 2);
                int px = rem >> 1, half = rem & 1;
                int yin = (DIL == 1) ? (y0 - 1 + r)
                                     : (y0 + (r & 1) + ((r >> 1) - 1) * DIL);
                const f16* src = inb
                    + (((size_t)(yin + inPad) * inCiT + kt) * inXe + (inPad - DIL + px)) * 16
                    + half * 8;
                gld16(src, sb + cc * 16);
            }
        }
    };

    f32x16 acc[PXW][MFW] = {};

    stage(0, 0);
    __syncthreads();
    for (int kt = 0; kt < Ci16; ++kt) {
        if (kt + 1 < Ci16) stage(kt + 1, (kt + 1) & 1);
        const char* sb = smem + (kt & 1) * CHB;
        const f16* wkt = wp + (size_t)kt * 9 * CoPad * 16 + hi * 8;

        if constexpr (MFW == 1) {
            f16x8 wfr[9];
#pragma unroll
            for (int k9 = 0; k9 < 9; ++k9)
                wfr[k9] = *(const f16x8*)(wkt + (size_t)k9 * CoPad * 16 +
                                          (cb0 + 32 * c + col) * 16);
#pragma unroll
            for (int ky = 0; ky < 3; ++ky) {
#pragma unroll
                for (int kx = 0; kx < 3; ++kx) {
                    const int rrow = (DIL == 1) ? (t + ky) : (ky * 2 + t);
#pragma unroll
                    for (int p = 0; p < PXW; ++p) {
                        const f16x8 bfrag = *(const f16x8*)(sb +
                            ((rrow * Wext + 32 * (PXW * pp + p) + col + kx * DIL) * 32 + hi * 16));
                        acc[p][0] = __builtin_amdgcn_mfma_f32_32x32x16_f16(
                            wfr[ky * 3 + kx], bfrag, acc[p][0], 0, 0, 0);
                    }
                }
            }
        } else {
#pragma unroll
            for (int ky = 0; ky < 3; ++ky) {
#pragma unroll
                for (int kx = 0; kx < 3; ++kx) {
                    const int rrow = (DIL == 1) ? (t + ky) : (ky * 2 + t);
                    f16x8 bfr[PXW];
#pragma unroll
                    for (int p = 0; p < PXW; ++p)
                        bfr[p] = *(const f16x8*)(sb +
                            ((rrow * Wext + 32 * (PXW * pp + p) + col + kx * DIL) * 32 + hi * 16));
                    const f16* wtap = wkt + (size_t)(ky * 3 + kx) * CoPad * 16;
#pragma unroll
                    for (int m = 0; m < MFW; ++m) {
                        const f16x8 afrag =
                            *(const f16x8*)(wtap + (cb0 + 32 * (c * MFW + m) + col) * 16);
#pragma unroll
                        for (int p = 0; p < PXW; ++p)
                            acc[p][m] = __builtin_amdgcn_mfma_f32_32x32x16_f16(
                                afrag, bfr[p], acc[p][m], 0, 0, 0);
                    }
                }
            }
        }
        __syncthreads();
    }

    // ---- epilogue ----
    const int y = y0 + t;
    if constexpr (MODE == 0) {
        const size_t prow = (size_t)(b * outYe + (y + outPad)) * outCoT;
#pragma unroll
        for (int p = 0; p < PXW; ++p) {
            const int x = 32 * (PXW * pp + p) + col;
#pragma unroll
            for (int m = 0; m < MFW; ++m) {
#pragma unroll
                for (int eq = 0; eq < 4; ++eq) {
                    const int co = cb0 + 32 * (c * MFW + m) + 8 * eq + 4 * hi;
                    f16x4 h;
#pragma unroll
                    for (int s = 0; s < 4; ++s) {
                        float v = acc[p][m][4 * eq + s] + bias[co + s];
                        v = (v >= 0.f) ? v : 0.1f * v;
                        h[s] = (f16)v;
                    }
                    *(f16x4*)(out + ((prow + (co >> 4)) * outXe + (outPad + x)) * 16
                                  + (co & 15)) = h;
                }
            }
        }
    } else {
        if (hi == 0) {
            const int x = 32 * pp + col;
#pragma unroll
            for (int s = 0; s < 2; ++s) {
                float v = acc[0][0][s] + bias[s];
                const size_t oi = (((size_t)b * 2 + s) * 128 + y) * 128 + x;
                if constexpr (MODE == 1) {
                    dout[oi] = v;
                    const int ch = outCoOff + s;
                    const size_t prow = (size_t)(b * outYe + (y + outPad)) * outCoT;
                    out[((prow + (ch >> 4)) * outXe + (outPad + x)) * 16 + (ch & 15)] = (f16)v;
                } else {
                    v = (v >= 0.f) ? v : 0.1f * v;
                    dout[oi] += v;
                }
            }
        }
    }
}

// ---------------------------------------------------------------------------
// Correlation (r14 champion): all 9 dy per block, acc[9][9] ILP, channel-pair
// layouts, v_dot2_f32_f16, scalar 4B loads, x = lane dim.
// Writes f16 into IN0 channels 128..208 (now cit-tiled layout).
// ---------------------------------------------------------------------------
__global__ __launch_bounds__(256, 2) void corr_k(const h2* __restrict__ px1,
                                                 const h2* __restrict__ px2,
                                                 f16* __restrict__ in0) {
    const int g = blockIdx.x;                  // bijective XCD swizzle
    const int n = (g & 7) * 64 + (g >> 3);
    const int b = n >> 6;
    const int x = threadIdx.x & 127;
    const int y = (n & 63) * 2 + (threadIdx.x >> 7);

    const h2* p1  = px1 + (size_t)b * 64 * HW16K + y * 128 + x;
    const h2* p2b = px2 + (size_t)b * 64 * 18496 + (size_t)y * 136 + x;

    float acc[9][9] = {};
    for (int cp = 0; cp < 64; ++cp) {
        const h2 v1 = p1[(size_t)cp * HW16K];
        const h2* base = p2b + (size_t)cp * 18496;
#pragma unroll
        for (int j = 0; j < 9; ++j) {
            const h2* row = base + j * 136;
#pragma unroll
            for (int d = 0; d < 9; ++d)
                acc[j][d] = __builtin_amdgcn_fdot2(v1, row[d], acc[j][d], false);
        }
    }
    const size_t prow = (size_t)(b * 130 + (y + 1)) * 14;
#pragma unroll
    for (int j = 0; j < 9; ++j)
#pragma unroll
        for (int d = 0; d < 9; ++d) {
            const int o = j * 9 + d;
            in0[((prow + 8 + (o >> 4)) * 130 + (x + 1)) * 16 + (o & 15)] =
                (f16)(acc[j][d] * (1.f / 128.f));
        }
}

// x1 fp32 NCHW -> IN0 (cit-tiled) ch0..127 AND PX1 channel-pair layout
__global__ __launch_bounds__(256) void x1pack(const float* __restrict__ x1,
                                              f16* __restrict__ in0,
                                              h2* __restrict__ px1) {
    const int x = threadIdx.x & 127;
    const int y = blockIdx.x * 2 + (threadIdx.x >> 7);
    const int b = blockIdx.z;
    const float* p1 = x1 + (size_t)b * 128 * HW16K + y * 128 + x;
    h2* q = px1 + (size_t)b * 64 * HW16K + y * 128 + x;
    const size_t prow = (size_t)(b * 130 + (y + 1)) * 14;
    for (int cp = 0; cp < 64; ++cp) {
        const float a0 = p1[(2 * cp) * HW16K];
        const float a1 = p1[(2 * cp + 1) * HW16K];
        h2 v; v[0] = (f16)a0; v[1] = (f16)a1;
        q[(size_t)cp * HW16K] = v;
        const int ch = 2 * cp;
        *(h2*)(in0 + ((prow + (ch >> 4)) * 130 + (x + 1)) * 16 + (ch & 15)) = v;
    }
}

// x2 fp32 NCHW -> PX2 padded channel-pair layout (writes zeros in border)
__global__ __launch_bounds__(256) void x2pack(const float* __restrict__ x2,
                                              h2* __restrict__ px2) {
    const int cell = blockIdx.x * 256 + threadIdx.x;   // over 136x136
    if (cell >= 136 * 136) return;
    const int yp = cell / 136, xp = cell - yp * 136;
    const int cp = blockIdx.y, b = blockIdx.z;
    h2 v; v[0] = (f16)0.f; v[1] = (f16)0.f;
    const int yy = yp - 4, xx = xp - 4;
    if ((unsigned)yy < 128u && (unsigned)xx < 128u) {
        const float* p = x2 + (size_t)b * 128 * HW16K + (2 * cp) * HW16K + yy * 128 + xx;
        v[0] = (f16)p[0];
        v[1] = (f16)p[HW16K];
    }
    px2[((size_t)(b * 64 + cp) * 136 + yp) * 136 + xp] = v;
}

// zero spatial border of a cit-tiled buffer [B][Ye][CiT][Xe][16]
__global__ void zero_border(f16* buf, int Ye, int Xe, int CiT, int pad) {
    const int cell = blockIdx.x * 256 + threadIdx.x;
    const int total = Ye * Xe;
    if (cell >= total) return;
    const int yy = cell / Xe, xx = cell - yy * Xe;
    if (yy >= pad && yy < Ye - pad && xx >= pad && xx < Xe - pad) return;
    f16x8 z = {};
    for (int ct = 0; ct < CiT; ++ct) {
        f16* p = buf + (((size_t)(blockIdx.z * Ye + yy) * CiT + ct) * Xe + xx) * 16;
        *(f16x8*)(p) = z;
        *(f16x8*)(p + 8) = z;
    }
}

// all 13 weight tensors: fp32 OIHW -> f16 [kt][tap][CoPad][16], zero-padded
struct PPA {
    const float* src[13];
    f16* dst[13];
    int Co[13], Ci[13], CoPad[13], CiPad[13];
};
__global__ void prepack_all(PPA a) {
    const int l = blockIdx.z;
    const int CoPad = a.CoPad[l], CiPad = a.CiPad[l];
    const int total = 9 * CoPad * CiPad;
    const int i = blockIdx.x * 256 + threadIdx.x;
    if (i >= total) return;
    const int k  = i / (CoPad * CiPad);
    const int r  = i - k * CoPad * CiPad;
    const int co = r / CiPad;
    const int ci = r - co * CiPad;
    f16 v = (f16)0.f;
    if (co < a.Co[l] && ci < a.Ci[l])
        v = (f16)a.src[l][((size_t)co * a.Ci[l] + ci) * 9 + k];
    const int kt = ci >> 4, cin = ci & 15;
    a.dst[l][(((size_t)kt * 9 + k) * CoPad + co) * 16 + cin] = v;
}

extern "C" void kernel_launch(void* const* d_in, const int* in_sizes, int n_in,
                              void* d_out, int out_size, void* d_ws, size_t ws_size,
                              hipStream_t stream) {
    const float* x1 = (const float*)d_in[0];
    const float* x2 = (const float*)d_in[1];
    const float* W[13]  = {(const float*)d_in[2],  (const float*)d_in[4],  (const float*)d_in[6],
                           (const float*)d_in[8],  (const float*)d_in[10], (const float*)d_in[12],
                           (const float*)d_in[14], (const float*)d_in[16], (const float*)d_in[18],
                           (const float*)d_in[20], (const float*)d_in[22], (const float*)d_in[24],
                           (const float*)d_in[26]};
    const float* Bs[13] = {(const float*)d_in[3],  (const float*)d_in[5],  (const float*)d_in[7],
                           (const float*)d_in[9],  (const float*)d_in[11], (const float*)d_in[13],
                           (const float*)d_in[15], (const float*)d_in[17], (const float*)d_in[19],
                           (const float*)d_in[21], (const float*)d_in[23], (const float*)d_in[25],
                           (const float*)d_in[27]};
    float* outp = (float*)d_out;

    // ---- workspace layout (bytes) ----  (same sizes; internal order cit-tiled)
    char* ws = (char*)d_ws;
    f16* IN0 = (f16*)(ws);                       // [8][130][14][130][16] = 60,569,600 B
    f16* P   = (f16*)(ws + 60569600);            // [8][144][8][144][16]  = 42,467,328 B
    f16* Q   = (f16*)(ws + 103036928);           // [8][160][8][160][16]  = 52,428,800 B
    f16* CC  = (f16*)(ws + 155465728);           // [8][130][4][130][16]  = 17,305,600 B
    char* WPB = ws + 172771328;
    // PX1/PX2 alias P/Q: consumed by corr BEFORE any conv writes P/Q.
    h2* PX1 = (h2*)P;
    h2* PX2 = (h2*)Q;

    // per-layer: {Co, Ci, CoPad, CiPad}
    const int LC[13][4] = {
        {128, 209, 128, 224}, {128, 128, 128, 128}, {96, 128, 96, 128},
        {64, 96, 64, 96},     {32, 64, 32, 64},     {2, 32, 32, 32},
        {128, 34, 128, 64},   {128, 128, 128, 128}, {128, 128, 128, 128},
        {96, 128, 96, 128},   {64, 96, 64, 96},     {32, 64, 32, 64},
        {2, 32, 32, 32}};
    f16* wpp[13];
    PPA pa;
    {
        size_t off = 0;
        for (int l = 0; l < 13; ++l) {
            wpp[l] = (f16*)(WPB + off);
            off += (size_t)9 * LC[l][2] * LC[l][3] * 2;
            pa.src[l] = W[l]; pa.dst[l] = wpp[l];
            pa.Co[l] = LC[l][0]; pa.Ci[l] = LC[l][1];
            pa.CoPad[l] = LC[l][2]; pa.CiPad[l] = LC[l][3];
        }
    }

    const dim3 blk(256, 1, 1);
    const dim3 blk512(512, 1, 1);

    // weights (single fused launch) + borders of non-aliased buffers
    prepack_all<<<dim3(1008, 1, 13), blk, 0, stream>>>(pa);
    zero_border<<<dim3(67, 1, 8), blk, 0, stream>>>(IN0, 130, 130, 14, 1);
    zero_border<<<dim3(67, 1, 8), blk, 0, stream>>>(CC, 130, 130, 4, 1);

    // pack inputs + correlation
    x1pack<<<dim3(64, 1, 8), blk, 0, stream>>>(x1, IN0, PX1);
    x2pack<<<dim3(73, 64, 8), blk, 0, stream>>>(x2, PX2);
    corr_k<<<dim3(512, 1, 1), blk, 0, stream>>>(PX1, PX2, IN0);

    // PX1/PX2 dead -> restore P/Q borders
    zero_border<<<dim3(81, 1, 8),  blk, 0, stream>>>(P, 144, 144, 8, 8);
    zero_border<<<dim3(100, 1, 8), blk, 0, stream>>>(Q, 160, 160, 8, 16);

    // ---- flow estimator ----
    conv_mfma<1, 2, 2, 0><<<dim3(512, 1, 1), blk512, 0, stream>>>(IN0, 130, 130, 14, 1, wpp[0], Bs[0],
                                                  P, 144, 144, 8, 8, 0, nullptr, 14, 128);
    conv_mfma<1, 2, 2, 0><<<dim3(512, 1, 1), blk512, 0, stream>>>(P, 144, 144, 8, 8, wpp[1], Bs[1],
                                                  Q, 160, 160, 8, 16, 0, nullptr, 8, 128);
    conv_mfma<1, 1, 3, 0><<<dim3(512, 1, 1), blk512, 0, stream>>>(Q, 160, 160, 8, 16, wpp[2], Bs[2],
                                                  P, 144, 144, 8, 8, 0, nullptr, 8, 96);
    conv_mfma<1, 1, 2, 0><<<dim3(512, 1, 1), blk512, 0, stream>>>(P, 144, 144, 8, 8, wpp[3], Bs[3],
                                                  Q, 160, 160, 8, 16, 0, nullptr, 6, 64);
    conv_mfma<1, 1, 1, 0><<<dim3(512, 1, 1), blk512, 0, stream>>>(Q, 160, 160, 8, 16, wpp[4], Bs[4],
                                                  CC, 130, 130, 4, 1, 0, nullptr, 4, 32);
    // flow head: reads CC ch0..31, writes d_out fp32 + CC ch32/33
    conv_mfma<1, 1, 1, 1><<<dim3(512, 1, 1), blk512, 0, stream>>>(CC, 130, 130, 4, 1, wpp[5], Bs[5],
                                                  CC, 130, 130, 4, 1, 32, outp, 2, 32);
    // ---- context network ----
    conv_mfma<1, 2, 2, 0><<<dim3(512, 1, 1), blk512, 0, stream>>>(CC, 130, 130, 4, 1, wpp[6], Bs[6],
                                                  P, 144, 144, 8, 8, 0, nullptr, 4, 128);
    conv_mfma<2, 2, 2, 0><<<dim3(512, 1, 1), blk512, 0, stream>>>(P, 144, 144, 8, 8, wpp[7], Bs[7],
                                                  Q, 160, 160, 8, 16, 0, nullptr, 8, 128);
    conv_mfma<4, 2, 2, 0><<<dim3(512, 1, 1), blk512, 0, stream>>>(Q, 160, 160, 8, 16, wpp[8], Bs[8],
                                                  P, 144, 144, 8, 8, 0, nullptr, 8, 128);
    conv_mfma<8, 1, 3, 0><<<dim3(512, 1, 1), blk512, 0, stream>>>(P, 144, 144, 8, 8, wpp[9], Bs[9],
                                                  Q, 160, 160, 8, 16, 0, nullptr, 8, 96);
    conv_mfma<16, 1, 2, 0><<<dim3(512, 1, 1), blk512, 0, stream>>>(Q, 160, 160, 8, 16, wpp[10], Bs[10],
                                                   P, 144, 144, 8, 8, 0, nullptr, 6, 64);
    conv_mfma<1, 1, 1, 0><<<dim3(512, 1, 1), blk512, 0, stream>>>(P, 144, 144, 8, 8, wpp[11], Bs[11],
                                                  Q, 160, 160, 8, 16, 0, nullptr, 4, 32);
    // final: 32->2, leaky, += flo (d_out)
    conv_mfma<1, 1, 1, 2><<<dim3(512, 1, 1), blk512, 0, stream>>>(Q, 160, 160, 8, 16, wpp[12], Bs[12],
                                                  nullptr, 0, 0, 0, 0, 0, outp, 2, 32);
}